// Round 14
// baseline (1853.342 us; speedup 1.0000x reference)
//
#include <hip/hip_runtime.h>
#include <stdint.h>

#define DX 1024
#define NB 64
#define DY 10
#define NJK 100

typedef unsigned short ushort_t;
typedef __attribute__((ext_vector_type(8))) short short8;
typedef __attribute__((ext_vector_type(4))) int int4v;
typedef __attribute__((ext_vector_type(16))) int int16v;
typedef __attribute__((ext_vector_type(4))) float f32x4;

#define S1Q 21.0f
#define S2Q 5248.0f
#define INV_HH (1.0f / (21.0f * 21.0f))
#define INV_MIX (1.0f / (21.0f * 5248.0f))

#define VMCNT4 asm volatile("s_waitcnt vmcnt(4)" ::: "memory")
#define VMCNT3 asm volatile("s_waitcnt vmcnt(3)" ::: "memory")
#define VMCNT2 asm volatile("s_waitcnt vmcnt(2)" ::: "memory")
#define VMCNT0 asm volatile("s_waitcnt vmcnt(0)" ::: "memory")
#define LGKM0 asm volatile("s_waitcnt lgkmcnt(0)" ::: "memory")
#define CFENCE asm volatile("" ::: "memory")

__device__ __forceinline__ unsigned short f2bf(float f) {
  unsigned int u = __builtin_bit_cast(unsigned int, f);
  u += 0x7fffu + ((u >> 16) & 1u);
  return (unsigned short)(u >> 16);
}
__device__ __forceinline__ float bf2f(unsigned short h) {
  unsigned int u = ((unsigned int)h) << 16;
  return __builtin_bit_cast(float, u);
}
__device__ __forceinline__ void gload16(const void* g, void* l) {
  __builtin_amdgcn_global_load_lds((const __attribute__((address_space(1))) unsigned int*)g,
                                   (__attribute__((address_space(3))) unsigned int*)l, 16, 0, 0);
}

// ---------------------------------------------------------------------------
// P0rho (R12 verbatim): R2[p][jk(112)][m] bf16 + S[p][m] diagonal (f32).
// ---------------------------------------------------------------------------
__launch_bounds__(256)
__global__ void p0_rho(const float* __restrict__ rho, ushort_t* __restrict__ R2,
                       float* __restrict__ S) {
  __shared__ ushort_t R_s[112 * 128];
  int p = blockIdx.x;
  int t = threadIdx.x;
  const float* rp = rho + (size_t)p * (DY * DX * DY);
  ushort_t* R2p = R2 + (size_t)p * (112 * 1024);
  int m = t >> 1, h = t & 1;

  for (int mc = 0; mc < 8; ++mc) {
    __syncthreads();
    float ssum = 0.f;
#pragma unroll
    for (int j = 0; j < DY; ++j) {
      const float* bj = rp + (size_t)j * (DX * DY) + (size_t)(mc * 128 + m) * DY;
      const float4 q = *(const float4*)(bj + h * 4);
      const float e = bj[8 + h];
      int rb = j * DY + h * 4;
      R_s[((rb + 0) * 128 + m) ^ (((rb + 0) & 15) << 3)] = f2bf(q.x);
      R_s[((rb + 1) * 128 + m) ^ (((rb + 1) & 15) << 3)] = f2bf(q.y);
      R_s[((rb + 2) * 128 + m) ^ (((rb + 2) & 15) << 3)] = f2bf(q.z);
      R_s[((rb + 3) * 128 + m) ^ (((rb + 3) & 15) << 3)] = f2bf(q.w);
      int r8 = j * DY + 8 + h;
      R_s[(r8 * 128 + m) ^ ((r8 & 15) << 3)] = f2bf(e);
      if (h == 0) {
        if (j == 0) ssum += q.x;
        if (j == 1) ssum += q.y;
        if (j == 2) ssum += q.z;
        if (j == 3) ssum += q.w;
        if (j == 8) ssum += e;
      } else {
        if (j == 4) ssum += q.x;
        if (j == 5) ssum += q.y;
        if (j == 6) ssum += q.z;
        if (j == 7) ssum += q.w;
        if (j == 9) ssum += e;
      }
    }
    ssum += __shfl_xor(ssum, 1, 64);
    if (h == 0) S[(size_t)p * DX + mc * 128 + m] = ssum;
    __syncthreads();
#pragma unroll
    for (int i = 0; i < 7; ++i) {
      int c = i * 256 + t;
      int row = c >> 4, sl = c & 15;
      uint4 v = make_uint4(0u, 0u, 0u, 0u);
      if (row < NJK) v = *(const uint4*)&R_s[(row * 128 + sl * 8) ^ ((row & 15) << 3)];
      *(uint4*)(R2p + (size_t)row * 1024 + mc * 128 + sl * 8) = v;
    }
  }
}

// ---------------------------------------------------------------------------
// P0a: int8 split of X and X^T, 128B row records:
//  XHL8 [b][kt(16)][m(1024)][h k0..63 | l k0..63]  (x = h/21 + l/5248)
//  XtHL8[b][kt(16)][p(1024)][same for X^T rows]
// One 64x64 tile = exactly one kt block for each output.
// ---------------------------------------------------------------------------
__launch_bounds__(256)
__global__ void p0_split(const float* __restrict__ X,
                         ushort_t* __restrict__ XHL, ushort_t* __restrict__ XtHL) {
  __shared__ float T[64][65];
  int blk = blockIdx.x;
  int bl = blk >> 8;
  int tt = blk & 255;
  int r0 = (tt >> 4) << 6;
  int c0 = (tt & 15) << 6;
  const float* Xb = X + (size_t)bl * DX * DX;
  int t = threadIdx.x;
  int r = t >> 4, c = t & 15;
#pragma unroll
  for (int s = 0; s < 4; ++s) {
    const float4 v = *(const float4*)(Xb + (size_t)(r0 + r + 16 * s) * DX + c0 + c * 4);
    T[r + 16 * s][c * 4 + 0] = v.x;
    T[r + 16 * s][c * 4 + 1] = v.y;
    T[r + 16 * s][c * 4 + 2] = v.z;
    T[r + 16 * s][c * 4 + 3] = v.w;
  }
  __syncthreads();
  int s8 = t & 7;
  int rw = t >> 3;
  int plane = s8 >> 2, qq = s8 & 3;
#pragma unroll
  for (int sp = 0; sp < 2; ++sp) {
    int loc = rw + sp * 32;
    // XHL8: row m = r0+loc, kt = c0>>6, k-local = qq*16+e
    {
      unsigned v[4] = {0u, 0u, 0u, 0u};
#pragma unroll
      for (int e = 0; e < 16; ++e) {
        float x = T[loc][qq * 16 + e];
        float hq = fminf(fmaxf(rintf(x * S1Q), -127.f), 127.f);
        float val = (plane == 0)
                        ? hq
                        : fminf(fmaxf(rintf((x - hq * (1.0f / S1Q)) * S2Q), -127.f), 127.f);
        int iv = (int)val;
        v[e >> 2] |= ((unsigned)(unsigned char)(signed char)iv) << ((e & 3) * 8);
      }
      int kt = c0 >> 6;
      size_t off = (((size_t)bl * 16 + kt) * 1024 + (r0 + loc)) * 64 + s8 * 8;
      *(uint4*)(XHL + off) = make_uint4(v[0], v[1], v[2], v[3]);
    }
    // XtHL8: row p = c0+loc, kt = r0>>6, x = T[k_local][loc]
    {
      unsigned v[4] = {0u, 0u, 0u, 0u};
#pragma unroll
      for (int e = 0; e < 16; ++e) {
        float x = T[qq * 16 + e][loc];
        float hq = fminf(fmaxf(rintf(x * S1Q), -127.f), 127.f);
        float val = (plane == 0)
                        ? hq
                        : fminf(fmaxf(rintf((x - hq * (1.0f / S1Q)) * S2Q), -127.f), 127.f);
        int iv = (int)val;
        v[e >> 2] |= ((unsigned)(unsigned char)(signed char)iv) << ((e & 3) * 8);
      }
      int kt = r0 >> 6;
      size_t off = (((size_t)bl * 16 + kt) * 1024 + (c0 + loc)) * 64 + s8 * 8;
      *(uint4*)(XtHL + off) = make_uint4(v[0], v[1], v[2], v[3]);
    }
  }
}

// ---------------------------------------------------------------------------
// K1: A[b]=X[b]@X[b], 3-pass split-INT8 MFMA (exact i32 accumulation).
// 256x256 tile, BK=64, 16 kt, 8 waves (2x4), 8-phase K-step (R10 schedule),
// mfma_i32_32x32x32_i8.  accH = sum hh'; accM = sum(hl') + sum(lh').
// A = accH/441 + accM/110208 (f32 epilogue).
// Epilogue 1: exact trace partial <A,S>.  Epilogue 2: Ah bf16 -> [p][b][m].
// ---------------------------------------------------------------------------
__launch_bounds__(512, 2)
__global__ void k1_gemm(const ushort_t* __restrict__ XHL,
                        const ushort_t* __restrict__ XtHL,
                        const float* __restrict__ S,
                        ushort_t* __restrict__ Ahg,
                        float* __restrict__ part_tr, int bg) {
  __shared__ ushort_t lds[65536];  // 2 bufs x (A 16384 | B 16384) ushorts = 128 KB
  int wg = blockIdx.x;
  int cpx = gridDim.x >> 3;
  int gt = (wg & 7) * cpx + (wg >> 3);  // XCD-chunked
  int bl = gt >> 4, tile = gt & 15;
  int b = bg + bl;
  int m0 = (tile >> 2) << 8, p0 = (tile & 3) << 8;
  int t = threadIdx.x;
  int wv = t >> 6, lane = t & 63, l31 = lane & 31, hi8 = lane >> 5;
  int wm = (wv >> 2) << 7, wp = (wv & 3) << 6;

  int16v accH[4][2], accM[4][2];
#pragma unroll
  for (int mi = 0; mi < 4; ++mi)
#pragma unroll
    for (int ni = 0; ni < 2; ++ni)
#pragma unroll
      for (int e = 0; e < 16; ++e) {
        accH[mi][ni][e] = 0;
        accM[mi][ni][e] = 0;
      }

  int lam = lane >> 3;
  int lsl = (lane & 7) ^ lam;
  const ushort_t* Asrc = XHL + ((size_t)bl * 16 * 1024 + m0) * 64 + (size_t)lsl * 8;
  const ushort_t* Bsrc = XtHL + ((size_t)bl * 16 * 1024 + p0) * 64 + (size_t)lsl * 8;
  int ldsw = (t & ~63) * 8;

  auto stageA2 = [&](int kt, int half) {
    int buf = (kt & 1) << 15;
    size_t ko = (size_t)kt * 65536;
#pragma unroll
    for (int i = half * 2; i < half * 2 + 2; ++i) {
      int rr = (i << 6) + (wv << 3) + lam;
      gload16(Asrc + ko + (size_t)rr * 64, &lds[buf + (i << 12) + ldsw]);
    }
  };
  auto stageB2 = [&](int kt, int half) {
    int buf = (kt & 1) << 15;
    size_t ko = (size_t)kt * 65536;
#pragma unroll
    for (int i = half * 2; i < half * 2 + 2; ++i) {
      int rr = (i << 6) + (wv << 3) + lam;
      gload16(Bsrc + ko + (size_t)rr * 64, &lds[buf + 16384 + (i << 12) + ldsw]);
    }
  };
  auto readB = [&](int buf, int kc, int4v* bh, int4v* blo) {
#pragma unroll
    for (int ni = 0; ni < 2; ++ni) {
      int p = wp + (ni << 5) + l31;
      int rowb = buf + 16384 + p * 64;
      bh[ni] = *(const int4v*)&lds[rowb + (((kc * 2 + hi8) ^ (p & 7)) << 3)];
      blo[ni] = *(const int4v*)&lds[rowb + (((4 + kc * 2 + hi8) ^ (p & 7)) << 3)];
    }
  };
  auto readA2 = [&](int buf, int kc, int mi, int4v& a, int4v& l) {
    int m = wm + (mi << 5) + l31;
    int rowa = buf + m * 64;
    a = *(const int4v*)&lds[rowa + (((kc * 2 + hi8) ^ (m & 7)) << 3)];
    l = *(const int4v*)&lds[rowa + (((4 + kc * 2 + hi8) ^ (m & 7)) << 3)];
  };
  auto mfma6 = [&](int mi, const int4v& a, const int4v& l,
                   const int4v* bh, const int4v* blo) {
    __builtin_amdgcn_s_setprio(1);
#pragma unroll
    for (int ni = 0; ni < 2; ++ni) {
      accH[mi][ni] = __builtin_amdgcn_mfma_i32_32x32x32_i8(a, bh[ni], accH[mi][ni], 0, 0, 0);
      accM[mi][ni] = __builtin_amdgcn_mfma_i32_32x32x32_i8(a, blo[ni], accM[mi][ni], 0, 0, 0);
      accM[mi][ni] = __builtin_amdgcn_mfma_i32_32x32x32_i8(l, bh[ni], accM[mi][ni], 0, 0, 0);
    }
    __builtin_amdgcn_s_setprio(0);
  };

  stageA2(0, 0);
  stageA2(0, 1);
  stageB2(0, 0);
  stageB2(0, 1);
  VMCNT0;
  __builtin_amdgcn_s_barrier();

#pragma unroll 1
  for (int kt = 0; kt < 16; ++kt) {
    int buf = (kt & 1) << 15;
    int4v bh[2], blo[2], a, l;
    // ph0: readB(kc0)+A mi0; stage A(kt+1) half0
    readB(buf, 0, bh, blo);
    readA2(buf, 0, 0, a, l);
    if (kt < 15) stageA2(kt + 1, 0);
    CFENCE; __builtin_amdgcn_s_barrier(); LGKM0; __builtin_amdgcn_sched_barrier(0);
    mfma6(0, a, l, bh, blo);
    // ph1: A mi1; stage A(kt+1) half1
    readA2(buf, 0, 1, a, l);
    if (kt < 15) stageA2(kt + 1, 1);
    CFENCE; __builtin_amdgcn_s_barrier(); LGKM0; __builtin_amdgcn_sched_barrier(0);
    mfma6(1, a, l, bh, blo);
    // ph2: A mi2; stage B(kt+1) half0
    readA2(buf, 0, 2, a, l);
    if (kt < 15) stageB2(kt + 1, 0);
    CFENCE; __builtin_amdgcn_s_barrier(); LGKM0; __builtin_amdgcn_sched_barrier(0);
    mfma6(2, a, l, bh, blo);
    // ph3: A mi3; stage B(kt+1) half1
    readA2(buf, 0, 3, a, l);
    if (kt < 15) stageB2(kt + 1, 1);
    CFENCE; __builtin_amdgcn_s_barrier(); LGKM0; __builtin_amdgcn_sched_barrier(0);
    mfma6(3, a, l, bh, blo);
    // ph4: readB(kc1)+A mi0
    readB(buf, 1, bh, blo);
    readA2(buf, 1, 0, a, l);
    CFENCE; __builtin_amdgcn_s_barrier(); LGKM0; __builtin_amdgcn_sched_barrier(0);
    mfma6(0, a, l, bh, blo);
    // ph5: A mi1; vmcnt(4): A(kt+1) landed
    readA2(buf, 1, 1, a, l);
    if (kt < 15) { VMCNT4; }
    CFENCE; __builtin_amdgcn_s_barrier(); LGKM0; __builtin_amdgcn_sched_barrier(0);
    mfma6(1, a, l, bh, blo);
    // ph6: A mi2
    readA2(buf, 1, 2, a, l);
    CFENCE; __builtin_amdgcn_s_barrier(); LGKM0; __builtin_amdgcn_sched_barrier(0);
    mfma6(2, a, l, bh, blo);
    // ph7: A mi3; vmcnt(0): B(kt+1) landed
    readA2(buf, 1, 3, a, l);
    VMCNT0;
    CFENCE; __builtin_amdgcn_s_barrier(); LGKM0; __builtin_amdgcn_sched_barrier(0);
    mfma6(3, a, l, bh, blo);
  }

  // ---- epilogue 1: EXACT trace partial from reconstructed f32 A ----
  float tracc = 0.f;
#pragma unroll
  for (int mi = 0; mi < 4; ++mi)
#pragma unroll
    for (int ni = 0; ni < 2; ++ni) {
      int p = p0 + wp + (ni << 5) + l31;
#pragma unroll
      for (int rg = 0; rg < 4; ++rg) {
        int m = m0 + wm + (mi << 5) + 8 * rg + 4 * hi8;
        const float4 sv = *(const float4*)(S + (size_t)p * DX + m);
        float a0 = (float)accH[mi][ni][rg * 4 + 0] * INV_HH + (float)accM[mi][ni][rg * 4 + 0] * INV_MIX;
        float a1 = (float)accH[mi][ni][rg * 4 + 1] * INV_HH + (float)accM[mi][ni][rg * 4 + 1] * INV_MIX;
        float a2 = (float)accH[mi][ni][rg * 4 + 2] * INV_HH + (float)accM[mi][ni][rg * 4 + 2] * INV_MIX;
        float a3 = (float)accH[mi][ni][rg * 4 + 3] * INV_HH + (float)accM[mi][ni][rg * 4 + 3] * INV_MIX;
        tracc += a0 * sv.x + a1 * sv.y + a2 * sv.z + a3 * sv.w;
      }
    }
#pragma unroll
  for (int off = 32; off > 0; off >>= 1) tracc += __shfl_xor(tracc, off, 64);
  __syncthreads();
  if (lane == 0) ((float*)lds)[wv] = tracc;
  __syncthreads();
  if (t == 0) {
    float s = 0.f;
    for (int i = 0; i < 8; ++i) s += ((float*)lds)[i];
    part_tr[b * 16 + tile] = s;
  }
  __syncthreads();

  // ---- epilogue 2: Ah bf16 -> LDS [p][m] (swizzled) -> coalesced stores ----
#pragma unroll
  for (int mi = 0; mi < 4; ++mi)
#pragma unroll
    for (int ni = 0; ni < 2; ++ni) {
      int p = wp + (ni << 5) + l31;
#pragma unroll
      for (int rg = 0; rg < 4; ++rg) {
        int m = wm + (mi << 5) + 8 * rg + 4 * hi8;
        float a0 = (float)accH[mi][ni][rg * 4 + 0] * INV_HH + (float)accM[mi][ni][rg * 4 + 0] * INV_MIX;
        float a1 = (float)accH[mi][ni][rg * 4 + 1] * INV_HH + (float)accM[mi][ni][rg * 4 + 1] * INV_MIX;
        float a2 = (float)accH[mi][ni][rg * 4 + 2] * INV_HH + (float)accM[mi][ni][rg * 4 + 2] * INV_MIX;
        float a3 = (float)accH[mi][ni][rg * 4 + 3] * INV_HH + (float)accM[mi][ni][rg * 4 + 3] * INV_MIX;
        unsigned int h0 = f2bf(a0), h1 = f2bf(a1), h2 = f2bf(a2), h3 = f2bf(a3);
        int idx = p * 256 + (((m >> 3) ^ (p & 7)) << 3) + (m & 7);
        *(uint2*)&lds[idx] = make_uint2(h0 | (h1 << 16), h2 | (h3 << 16));
      }
    }
  __syncthreads();
#pragma unroll
  for (int i = 0; i < 16; ++i) {
    int cc = i * 512 + t;
    int row = cc >> 5, sl = cc & 31;
    int idx = row * 256 + ((sl ^ (row & 7)) << 3);
    uint4 v = *(const uint4*)&lds[idx];
    *(uint4*)(Ahg + ((size_t)(p0 + row) * NB + b) * DX + m0 + sl * 8) = v;
  }
}

// ---------------------------------------------------------------------------
// K2 (R12 verbatim): mc=32 chunks, 22.5 KB LDS, 4 blocks/CU.
// ---------------------------------------------------------------------------
__launch_bounds__(256)
__global__ void k2_contract(const ushort_t* __restrict__ R2,
                            const ushort_t* __restrict__ Ahg,
                            float* __restrict__ part_rho) {
  __shared__ ushort_t lds[11264];
  int p = blockIdx.x;
  int t = threadIdx.x;
  int wv = t >> 6, lane = t & 63, lr = lane & 15, lg = lane >> 4;
  const ushort_t* R2p = R2 + (size_t)p * (112 * 1024);
  const ushort_t* Ahp = Ahg + (size_t)p * (NB * DX);

  f32x4 acc[7];
#pragma unroll
  for (int n = 0; n < 7; ++n)
#pragma unroll
    for (int i = 0; i < 4; ++i) acc[n][i] = 0.f;

  auto stage = [&](int mc) {
    int buf = (mc & 1) * 5632;
    {
      int br = t >> 2, psl = t & 3;
      int lsl = psl ^ (br & 3);
      gload16(Ahp + (size_t)br * DX + mc * 32 + lsl * 8,
              &lds[buf + (t & ~63) * 8]);
    }
#pragma unroll
    for (int i = 0; i < 2; ++i) {
      int c = i * 256 + t;
      if (c < 448) {
        int row = c >> 2, psl = c & 3;
        int lsl = psl ^ (row & 3);
        gload16(R2p + (size_t)row * 1024 + mc * 32 + lsl * 8,
                &lds[buf + 2048 + (i * 256 + (t & ~63)) * 8]);
      }
    }
  };

  stage(0);
#pragma unroll 1
  for (int mc = 0; mc < 32; ++mc) {
    int buf = (mc & 1) * 5632;
    if (mc < 31) {
      stage(mc + 1);
      if (wv < 3) { VMCNT3; } else { VMCNT2; }
    } else {
      VMCNT0;
    }
    __builtin_amdgcn_s_barrier();
    CFENCE;
    {
      int ra = 16 * wv + lr;
      short8 af = *(const short8*)&lds[buf + ra * 32 + ((lg ^ (ra & 3)) << 3)];
      __builtin_amdgcn_s_setprio(1);
#pragma unroll
      for (int n = 0; n < 7; ++n) {
        int rb = 16 * n + lr;
        short8 bf = *(const short8*)&lds[buf + 2048 + rb * 32 + ((lg ^ (rb & 3)) << 3)];
        acc[n] = __builtin_amdgcn_mfma_f32_16x16x32_bf16(af, bf, acc[n], 0, 0, 0);
      }
      __builtin_amdgcn_s_setprio(0);
    }
    CFENCE;
    __builtin_amdgcn_s_barrier();
  }
#pragma unroll
  for (int n = 0; n < 7; ++n) {
    int col = 16 * n + lr;
    if (col < NJK) {
#pragma unroll
      for (int i = 0; i < 4; ++i) {
        int b_ = 16 * wv + lg * 4 + i;
        part_rho[((size_t)p * NB + b_) * NJK + col] = acc[n][i];
      }
    }
  }
}

// ---------------------------------------------------------------------------
// K3a: partial p-reduction; K3b: finish + divide by EXACT trace (16 parts).
// ---------------------------------------------------------------------------
__launch_bounds__(128)
__global__ void k3a(const float* __restrict__ part_rho, float* __restrict__ ws2) {
  int blk = blockIdx.x;
  int b = blk >> 1, h = blk & 1;
  int t = threadIdx.x;
  if (t >= NJK) return;
  float s = 0.f;
  for (int pp = 0; pp < 512; ++pp)
    s += part_rho[((size_t)(h * 512 + pp) * NB + b) * NJK + t];
  ws2[(size_t)(h * NB + b) * 128 + t] = s;
}

__launch_bounds__(128)
__global__ void k3b(const float* __restrict__ ws2, const float* __restrict__ part_tr,
                    float* __restrict__ out) {
  int b = blockIdx.x;
  int t = threadIdx.x;
  float tr = 0.f;
#pragma unroll
  for (int i = 0; i < 16; ++i) tr += part_tr[b * 16 + i];
  if (t < NJK) {
    float v = ws2[(size_t)b * 128 + t] + ws2[(size_t)(NB + b) * 128 + t];
    out[b * NJK + t] = v / tr;
  }
}

extern "C" void kernel_launch(void* const* d_in, const int* in_sizes, int n_in,
                              void* d_out, int out_size, void* d_ws, size_t ws_size,
                              hipStream_t stream) {
  const float* X = (const float*)d_in[0];
  const float* rho = (const float*)d_in[1];
  float* out = (float*)d_out;
  char* ws = (char*)d_ws;

  const size_t MB = 1048576ull;
  const size_t need_big = 612 * MB + 65536;
  const size_t need_small = 420 * MB + 65536;

  if (ws_size >= need_big) {
    ushort_t* XHL = (ushort_t*)(ws);              // 128 MiB (i8 pairs)
    ushort_t* XtHL = (ushort_t*)(ws + 128 * MB);  // 128 MiB
    ushort_t* Ahg = (ushort_t*)(ws + 256 * MB);   // 128 MiB
    ushort_t* R2 = (ushort_t*)(ws + 384 * MB);    // 224 MiB
    float* S = (float*)(ws + 608 * MB);           // 4 MiB
    float* part_tr = (float*)(ws + 612 * MB);     // 4 KiB
    float* part_rho = (float*)(ws);               // overlays XHL (dead after k1)
    float* ws2 = (float*)(ws + 32 * MB);

    hipLaunchKernelGGL(p0_rho, dim3(1024), dim3(256), 0, stream, rho, R2, S);
    hipLaunchKernelGGL(p0_split, dim3(16384), dim3(256), 0, stream, X, XHL, XtHL);
    hipLaunchKernelGGL(k1_gemm, dim3(1024), dim3(512), 0, stream, XHL, XtHL, S, Ahg, part_tr, 0);
    hipLaunchKernelGGL(k2_contract, dim3(1024), dim3(256), 0, stream, R2, Ahg, part_rho);
    hipLaunchKernelGGL(k3a, dim3(128), dim3(128), 0, stream, part_rho, ws2);
    hipLaunchKernelGGL(k3b, dim3(64), dim3(128), 0, stream, ws2, part_tr, out);
  } else {
    ushort_t* XHL = (ushort_t*)(ws);              // 32 MiB (per 16-batch group)
    ushort_t* XtHL = (ushort_t*)(ws + 32 * MB);   // 32 MiB
    ushort_t* Ahg = (ushort_t*)(ws + 64 * MB);    // 128 MiB
    ushort_t* R2 = (ushort_t*)(ws + 192 * MB);    // 224 MiB
    float* S = (float*)(ws + 416 * MB);           // 4 MiB
    float* part_tr = (float*)(ws + 420 * MB);     // 4 KiB
    float* part_rho = (float*)(ws + 64 * MB + 26 * MB);  // scratch past Ahg start? no:
    // part_rho (26 MiB) must not overlay live data: place after part_tr region
    // -> reuse XHL+XtHL (64 MiB, dead after last k1 group)
    part_rho = (float*)(ws);
    float* ws2 = (float*)(ws + 27 * MB);
    if (ws_size < need_small) return;

    hipLaunchKernelGGL(p0_rho, dim3(1024), dim3(256), 0, stream, rho, R2, S);
    for (int g = 0; g < 4; ++g) {
      hipLaunchKernelGGL(p0_split, dim3(4096), dim3(256), 0, stream,
                         X + (size_t)g * 16 * DX * DX, XHL, XtHL);
      hipLaunchKernelGGL(k1_gemm, dim3(256), dim3(512), 0, stream, XHL, XtHL, S, Ahg, part_tr, g * 16);
    }
    hipLaunchKernelGGL(k2_contract, dim3(1024), dim3(256), 0, stream, R2, Ahg, part_rho);
    hipLaunchKernelGGL(k3a, dim3(128), dim3(128), 0, stream, part_rho, ws2);
    hipLaunchKernelGGL(k3b, dim3(64), dim3(128), 0, stream, ws2, part_tr, out);
  }
}

// Round 15
// 620.698 us; speedup vs baseline: 2.9859x; 2.9859x over previous
//
#include <hip/hip_runtime.h>
#include <stdint.h>

#define DX 1024
#define NB 64
#define DY 10
#define NJK 100

typedef unsigned short ushort_t;
typedef __attribute__((ext_vector_type(8))) short short8;
typedef __attribute__((ext_vector_type(4))) int int4v;
typedef __attribute__((ext_vector_type(16))) int int16v;
typedef __attribute__((ext_vector_type(4))) float f32x4;

#define S1Q 21.0f
#define S2Q 5248.0f
#define INV_HH (1.0f / (21.0f * 21.0f))
#define INV_MIX (1.0f / (21.0f * 5248.0f))

#define VMCNT4 asm volatile("s_waitcnt vmcnt(4)" ::: "memory")
#define VMCNT3 asm volatile("s_waitcnt vmcnt(3)" ::: "memory")
#define VMCNT2 asm volatile("s_waitcnt vmcnt(2)" ::: "memory")
#define VMCNT0 asm volatile("s_waitcnt vmcnt(0)" ::: "memory")
#define LGKM0 asm volatile("s_waitcnt lgkmcnt(0)" ::: "memory")
#define CFENCE asm volatile("" ::: "memory")

__device__ __forceinline__ unsigned short f2bf(float f) {
  unsigned int u = __builtin_bit_cast(unsigned int, f);
  u += 0x7fffu + ((u >> 16) & 1u);
  return (unsigned short)(u >> 16);
}
__device__ __forceinline__ float bf2f(unsigned short h) {
  unsigned int u = ((unsigned int)h) << 16;
  return __builtin_bit_cast(float, u);
}
__device__ __forceinline__ void gload16(const void* g, void* l) {
  __builtin_amdgcn_global_load_lds((const __attribute__((address_space(1))) unsigned int*)g,
                                   (__attribute__((address_space(3))) unsigned int*)l, 16, 0, 0);
}

// ---------------------------------------------------------------------------
// P0rho (verbatim): R2[p][jk(112)][m] bf16 + S[p][m] diagonal (f32).
// ---------------------------------------------------------------------------
__launch_bounds__(256)
__global__ void p0_rho(const float* __restrict__ rho, ushort_t* __restrict__ R2,
                       float* __restrict__ S) {
  __shared__ ushort_t R_s[112 * 128];
  int p = blockIdx.x;
  int t = threadIdx.x;
  const float* rp = rho + (size_t)p * (DY * DX * DY);
  ushort_t* R2p = R2 + (size_t)p * (112 * 1024);
  int m = t >> 1, h = t & 1;

  for (int mc = 0; mc < 8; ++mc) {
    __syncthreads();
    float ssum = 0.f;
#pragma unroll
    for (int j = 0; j < DY; ++j) {
      const float* bj = rp + (size_t)j * (DX * DY) + (size_t)(mc * 128 + m) * DY;
      const float4 q = *(const float4*)(bj + h * 4);
      const float e = bj[8 + h];
      int rb = j * DY + h * 4;
      R_s[((rb + 0) * 128 + m) ^ (((rb + 0) & 15) << 3)] = f2bf(q.x);
      R_s[((rb + 1) * 128 + m) ^ (((rb + 1) & 15) << 3)] = f2bf(q.y);
      R_s[((rb + 2) * 128 + m) ^ (((rb + 2) & 15) << 3)] = f2bf(q.z);
      R_s[((rb + 3) * 128 + m) ^ (((rb + 3) & 15) << 3)] = f2bf(q.w);
      int r8 = j * DY + 8 + h;
      R_s[(r8 * 128 + m) ^ ((r8 & 15) << 3)] = f2bf(e);
      if (h == 0) {
        if (j == 0) ssum += q.x;
        if (j == 1) ssum += q.y;
        if (j == 2) ssum += q.z;
        if (j == 3) ssum += q.w;
        if (j == 8) ssum += e;
      } else {
        if (j == 4) ssum += q.x;
        if (j == 5) ssum += q.y;
        if (j == 6) ssum += q.z;
        if (j == 7) ssum += q.w;
        if (j == 9) ssum += e;
      }
    }
    ssum += __shfl_xor(ssum, 1, 64);
    if (h == 0) S[(size_t)p * DX + mc * 128 + m] = ssum;
    __syncthreads();
#pragma unroll
    for (int i = 0; i < 7; ++i) {
      int c = i * 256 + t;
      int row = c >> 4, sl = c & 15;
      uint4 v = make_uint4(0u, 0u, 0u, 0u);
      if (row < NJK) v = *(const uint4*)&R_s[(row * 128 + sl * 8) ^ ((row & 15) << 3)];
      *(uint4*)(R2p + (size_t)row * 1024 + mc * 128 + sl * 8) = v;
    }
  }
}

// ---------------------------------------------------------------------------
// P0a (R14 verbatim): int8 split records
//  XHL8 [b][kt(16)][m(1024)][h k0..63 | l k0..63]  (x = h/21 + l/5248)
//  XtHL8[b][kt(16)][p(1024)][same for X^T rows]
// ---------------------------------------------------------------------------
__launch_bounds__(256)
__global__ void p0_split(const float* __restrict__ X,
                         ushort_t* __restrict__ XHL, ushort_t* __restrict__ XtHL) {
  __shared__ float T[64][65];
  int blk = blockIdx.x;
  int bl = blk >> 8;
  int tt = blk & 255;
  int r0 = (tt >> 4) << 6;
  int c0 = (tt & 15) << 6;
  const float* Xb = X + (size_t)bl * DX * DX;
  int t = threadIdx.x;
  int r = t >> 4, c = t & 15;
#pragma unroll
  for (int s = 0; s < 4; ++s) {
    const float4 v = *(const float4*)(Xb + (size_t)(r0 + r + 16 * s) * DX + c0 + c * 4);
    T[r + 16 * s][c * 4 + 0] = v.x;
    T[r + 16 * s][c * 4 + 1] = v.y;
    T[r + 16 * s][c * 4 + 2] = v.z;
    T[r + 16 * s][c * 4 + 3] = v.w;
  }
  __syncthreads();
  int s8 = t & 7;
  int rw = t >> 3;
  int plane = s8 >> 2, qq = s8 & 3;
#pragma unroll
  for (int sp = 0; sp < 2; ++sp) {
    int loc = rw + sp * 32;
    {
      unsigned v[4] = {0u, 0u, 0u, 0u};
#pragma unroll
      for (int e = 0; e < 16; ++e) {
        float x = T[loc][qq * 16 + e];
        float hq = fminf(fmaxf(rintf(x * S1Q), -127.f), 127.f);
        float val = (plane == 0)
                        ? hq
                        : fminf(fmaxf(rintf((x - hq * (1.0f / S1Q)) * S2Q), -127.f), 127.f);
        int iv = (int)val;
        v[e >> 2] |= ((unsigned)(unsigned char)(signed char)iv) << ((e & 3) * 8);
      }
      int kt = c0 >> 6;
      size_t off = (((size_t)bl * 16 + kt) * 1024 + (r0 + loc)) * 64 + s8 * 8;
      *(uint4*)(XHL + off) = make_uint4(v[0], v[1], v[2], v[3]);
    }
    {
      unsigned v[4] = {0u, 0u, 0u, 0u};
#pragma unroll
      for (int e = 0; e < 16; ++e) {
        float x = T[qq * 16 + e][loc];
        float hq = fminf(fmaxf(rintf(x * S1Q), -127.f), 127.f);
        float val = (plane == 0)
                        ? hq
                        : fminf(fmaxf(rintf((x - hq * (1.0f / S1Q)) * S2Q), -127.f), 127.f);
        int iv = (int)val;
        v[e >> 2] |= ((unsigned)(unsigned char)(signed char)iv) << ((e & 3) * 8);
      }
      int kt = r0 >> 6;
      size_t off = (((size_t)bl * 16 + kt) * 1024 + (c0 + loc)) * 64 + s8 * 8;
      *(uint4*)(XtHL + off) = make_uint4(v[0], v[1], v[2], v[3]);
    }
  }
}

// ---------------------------------------------------------------------------
// K1: split-INT8, 128x256 block tile, 8 waves (2Mx4N), wave tile 64x64 ->
// accH+accM = 128 AGPR/lane (NO SPILL).  BK=64, 16 kt, 8-phase K-step:
// phases (kc,ni,mi); A-frags held across ni; stage {A,B0,B1}@ph0/1/2;
// drains vmcnt(4)@ph4, vmcnt(2)@ph6, vmcnt(0)@ph7.
// ---------------------------------------------------------------------------
__launch_bounds__(512, 2)
__global__ void k1_gemm(const ushort_t* __restrict__ XHL,
                        const ushort_t* __restrict__ XtHL,
                        const float* __restrict__ S,
                        ushort_t* __restrict__ Ahg,
                        float* __restrict__ part_tr, int bg) {
  __shared__ ushort_t lds[49152];  // 2 bufs x (A 8192 | B 16384) us = 96 KB
  int wg = blockIdx.x;
  int cpx = gridDim.x >> 3;
  int gt = (wg & 7) * cpx + (wg >> 3);  // XCD-chunked
  int bl = gt >> 5, tile = gt & 31;
  int b = bg + bl;
  int m0 = (tile >> 2) << 7, p0 = (tile & 3) << 8;
  int t = threadIdx.x;
  int wv = t >> 6, lane = t & 63, l31 = lane & 31, hi8 = lane >> 5;
  int wm = (wv >> 2) << 6, wp = (wv & 3) << 6;

  int16v accH[2][2], accM[2][2];
#pragma unroll
  for (int mi = 0; mi < 2; ++mi)
#pragma unroll
    for (int ni = 0; ni < 2; ++ni)
#pragma unroll
      for (int e = 0; e < 16; ++e) {
        accH[mi][ni][e] = 0;
        accM[mi][ni][e] = 0;
      }

  int lam = lane >> 3;
  int lsl = (lane & 7) ^ lam;
  const ushort_t* Asrc = XHL + ((size_t)bl * 16 * 1024 + m0) * 64 + (size_t)lsl * 8;
  const ushort_t* Bsrc = XtHL + ((size_t)bl * 16 * 1024 + p0) * 64 + (size_t)lsl * 8;
  int ldsw = (t & ~63) * 8;  // wv*512 ushorts per round

  auto stageA = [&](int kt) {  // 128 rows = 2 rounds
    int buf = (kt & 1) * 24576;
    size_t ko = (size_t)kt * 65536;
#pragma unroll
    for (int i = 0; i < 2; ++i) {
      int rr = (i << 6) + (wv << 3) + lam;
      gload16(Asrc + ko + (size_t)rr * 64, &lds[buf + (i << 12) + ldsw]);
    }
  };
  auto stageBh = [&](int kt, int half) {  // 256 rows = 4 rounds, 2 per half
    int buf = (kt & 1) * 24576;
    size_t ko = (size_t)kt * 65536;
#pragma unroll
    for (int i = half * 2; i < half * 2 + 2; ++i) {
      int rr = (i << 6) + (wv << 3) + lam;
      gload16(Bsrc + ko + (size_t)rr * 64, &lds[buf + 8192 + (i << 12) + ldsw]);
    }
  };
  auto readA2 = [&](int buf, int kc, int mi, int4v& a, int4v& l) {
    int m = wm + (mi << 5) + l31;
    int rowa = buf + m * 64;
    a = *(const int4v*)&lds[rowa + (((kc * 2 + hi8) ^ (m & 7)) << 3)];
    l = *(const int4v*)&lds[rowa + (((4 + kc * 2 + hi8) ^ (m & 7)) << 3)];
  };
  auto readB2 = [&](int buf, int kc, int ni, int4v& bh, int4v& blo) {
    int p = wp + (ni << 5) + l31;
    int rowb = buf + 8192 + p * 64;
    bh = *(const int4v*)&lds[rowb + (((kc * 2 + hi8) ^ (p & 7)) << 3)];
    blo = *(const int4v*)&lds[rowb + (((4 + kc * 2 + hi8) ^ (p & 7)) << 3)];
  };
  auto mfma3 = [&](int mi, int ni, const int4v& a, const int4v& l,
                   const int4v& bh, const int4v& blo) {
    __builtin_amdgcn_s_setprio(1);
    accH[mi][ni] = __builtin_amdgcn_mfma_i32_32x32x32_i8(a, bh, accH[mi][ni], 0, 0, 0);
    accM[mi][ni] = __builtin_amdgcn_mfma_i32_32x32x32_i8(a, blo, accM[mi][ni], 0, 0, 0);
    accM[mi][ni] = __builtin_amdgcn_mfma_i32_32x32x32_i8(l, bh, accM[mi][ni], 0, 0, 0);
    __builtin_amdgcn_s_setprio(0);
  };

  stageA(0);
  stageBh(0, 0);
  stageBh(0, 1);
  VMCNT0;
  __builtin_amdgcn_s_barrier();

#pragma unroll 1
  for (int kt = 0; kt < 16; ++kt) {
    int buf = (kt & 1) * 24576;
    int4v a0, l0, a1, l1, bh, blo;
    // ph0 (kc0,ni0,mi0): read B(0,0)+A(0,0); stage A(kt+1)
    readB2(buf, 0, 0, bh, blo);
    readA2(buf, 0, 0, a0, l0);
    if (kt < 15) stageA(kt + 1);
    CFENCE; __builtin_amdgcn_s_barrier(); LGKM0; __builtin_amdgcn_sched_barrier(0);
    mfma3(0, 0, a0, l0, bh, blo);
    // ph1 (kc0,ni0,mi1): read A(0,1); stage B(kt+1) half0
    readA2(buf, 0, 1, a1, l1);
    if (kt < 15) stageBh(kt + 1, 0);
    CFENCE; __builtin_amdgcn_s_barrier(); LGKM0; __builtin_amdgcn_sched_barrier(0);
    mfma3(1, 0, a1, l1, bh, blo);
    // ph2 (kc0,ni1,mi0): read B(0,1); stage B(kt+1) half1
    readB2(buf, 0, 1, bh, blo);
    if (kt < 15) stageBh(kt + 1, 1);
    CFENCE; __builtin_amdgcn_s_barrier(); LGKM0; __builtin_amdgcn_sched_barrier(0);
    mfma3(0, 1, a0, l0, bh, blo);
    // ph3 (kc0,ni1,mi1): no reads
    CFENCE; __builtin_amdgcn_s_barrier(); LGKM0; __builtin_amdgcn_sched_barrier(0);
    mfma3(1, 1, a1, l1, bh, blo);
    // ph4 (kc1,ni0,mi0): read B(1,0)+A(1,0); vmcnt(4): A(kt+1) landed
    readB2(buf, 1, 0, bh, blo);
    readA2(buf, 1, 0, a0, l0);
    if (kt < 15) { VMCNT4; }
    CFENCE; __builtin_amdgcn_s_barrier(); LGKM0; __builtin_amdgcn_sched_barrier(0);
    mfma3(0, 0, a0, l0, bh, blo);
    // ph5 (kc1,ni0,mi1): read A(1,1)
    readA2(buf, 1, 1, a1, l1);
    CFENCE; __builtin_amdgcn_s_barrier(); LGKM0; __builtin_amdgcn_sched_barrier(0);
    mfma3(1, 0, a1, l1, bh, blo);
    // ph6 (kc1,ni1,mi0): read B(1,1); vmcnt(2): B(kt+1) half0 landed
    readB2(buf, 1, 1, bh, blo);
    if (kt < 15) { VMCNT2; }
    CFENCE; __builtin_amdgcn_s_barrier(); LGKM0; __builtin_amdgcn_sched_barrier(0);
    mfma3(0, 1, a0, l0, bh, blo);
    // ph7 (kc1,ni1,mi1): vmcnt(0): all of kt+1 landed
    VMCNT0;
    CFENCE; __builtin_amdgcn_s_barrier(); LGKM0; __builtin_amdgcn_sched_barrier(0);
    mfma3(1, 1, a1, l1, bh, blo);
  }

  // ---- epilogue 1: EXACT trace partial from reconstructed f32 A ----
  float tracc = 0.f;
#pragma unroll
  for (int mi = 0; mi < 2; ++mi)
#pragma unroll
    for (int ni = 0; ni < 2; ++ni) {
      int p = p0 + wp + (ni << 5) + l31;
#pragma unroll
      for (int rg = 0; rg < 4; ++rg) {
        int m = m0 + wm + (mi << 5) + 8 * rg + 4 * hi8;
        const float4 sv = *(const float4*)(S + (size_t)p * DX + m);
        float a0 = (float)accH[mi][ni][rg * 4 + 0] * INV_HH + (float)accM[mi][ni][rg * 4 + 0] * INV_MIX;
        float a1 = (float)accH[mi][ni][rg * 4 + 1] * INV_HH + (float)accM[mi][ni][rg * 4 + 1] * INV_MIX;
        float a2 = (float)accH[mi][ni][rg * 4 + 2] * INV_HH + (float)accM[mi][ni][rg * 4 + 2] * INV_MIX;
        float a3 = (float)accH[mi][ni][rg * 4 + 3] * INV_HH + (float)accM[mi][ni][rg * 4 + 3] * INV_MIX;
        tracc += a0 * sv.x + a1 * sv.y + a2 * sv.z + a3 * sv.w;
      }
    }
#pragma unroll
  for (int off = 32; off > 0; off >>= 1) tracc += __shfl_xor(tracc, off, 64);
  __syncthreads();
  if (lane == 0) ((float*)lds)[wv] = tracc;
  __syncthreads();
  if (t == 0) {
    float s = 0.f;
    for (int i = 0; i < 8; ++i) s += ((float*)lds)[i];
    part_tr[b * 32 + tile] = s;
  }
  __syncthreads();

  // ---- epilogue 2: Ah bf16 -> LDS [p(256)][m(128)] swizzled -> stores ----
#pragma unroll
  for (int mi = 0; mi < 2; ++mi)
#pragma unroll
    for (int ni = 0; ni < 2; ++ni) {
      int p = wp + (ni << 5) + l31;
#pragma unroll
      for (int rg = 0; rg < 4; ++rg) {
        int m = wm + (mi << 5) + 8 * rg + 4 * hi8;
        float a0 = (float)accH[mi][ni][rg * 4 + 0] * INV_HH + (float)accM[mi][ni][rg * 4 + 0] * INV_MIX;
        float a1 = (float)accH[mi][ni][rg * 4 + 1] * INV_HH + (float)accM[mi][ni][rg * 4 + 1] * INV_MIX;
        float a2 = (float)accH[mi][ni][rg * 4 + 2] * INV_HH + (float)accM[mi][ni][rg * 4 + 2] * INV_MIX;
        float a3 = (float)accH[mi][ni][rg * 4 + 3] * INV_HH + (float)accM[mi][ni][rg * 4 + 3] * INV_MIX;
        unsigned int h0 = f2bf(a0), h1 = f2bf(a1), h2 = f2bf(a2), h3 = f2bf(a3);
        int idx = p * 128 + (((m >> 3) ^ (p & 15)) << 3) + (m & 7);
        *(uint2*)&lds[idx] = make_uint2(h0 | (h1 << 16), h2 | (h3 << 16));
      }
    }
  __syncthreads();
#pragma unroll
  for (int i = 0; i < 8; ++i) {
    int cc = i * 512 + t;
    int row = cc >> 4, sl = cc & 15;
    int idx = row * 128 + ((sl ^ (row & 15)) << 3);
    uint4 v = *(const uint4*)&lds[idx];
    *(uint4*)(Ahg + ((size_t)(p0 + row) * NB + b) * DX + m0 + sl * 8) = v;
  }
}

// ---------------------------------------------------------------------------
// K2 (R12 verbatim): mc=32 chunks, 22.5 KB LDS, 4 blocks/CU.
// ---------------------------------------------------------------------------
__launch_bounds__(256)
__global__ void k2_contract(const ushort_t* __restrict__ R2,
                            const ushort_t* __restrict__ Ahg,
                            float* __restrict__ part_rho) {
  __shared__ ushort_t lds[11264];
  int p = blockIdx.x;
  int t = threadIdx.x;
  int wv = t >> 6, lane = t & 63, lr = lane & 15, lg = lane >> 4;
  const ushort_t* R2p = R2 + (size_t)p * (112 * 1024);
  const ushort_t* Ahp = Ahg + (size_t)p * (NB * DX);

  f32x4 acc[7];
#pragma unroll
  for (int n = 0; n < 7; ++n)
#pragma unroll
    for (int i = 0; i < 4; ++i) acc[n][i] = 0.f;

  auto stage = [&](int mc) {
    int buf = (mc & 1) * 5632;
    {
      int br = t >> 2, psl = t & 3;
      int lsl = psl ^ (br & 3);
      gload16(Ahp + (size_t)br * DX + mc * 32 + lsl * 8,
              &lds[buf + (t & ~63) * 8]);
    }
#pragma unroll
    for (int i = 0; i < 2; ++i) {
      int c = i * 256 + t;
      if (c < 448) {
        int row = c >> 2, psl = c & 3;
        int lsl = psl ^ (row & 3);
        gload16(R2p + (size_t)row * 1024 + mc * 32 + lsl * 8,
                &lds[buf + 2048 + (i * 256 + (t & ~63)) * 8]);
      }
    }
  };

  stage(0);
#pragma unroll 1
  for (int mc = 0; mc < 32; ++mc) {
    int buf = (mc & 1) * 5632;
    if (mc < 31) {
      stage(mc + 1);
      if (wv < 3) { VMCNT3; } else { VMCNT2; }
    } else {
      VMCNT0;
    }
    __builtin_amdgcn_s_barrier();
    CFENCE;
    {
      int ra = 16 * wv + lr;
      short8 af = *(const short8*)&lds[buf + ra * 32 + ((lg ^ (ra & 3)) << 3)];
      __builtin_amdgcn_s_setprio(1);
#pragma unroll
      for (int n = 0; n < 7; ++n) {
        int rb = 16 * n + lr;
        short8 bf = *(const short8*)&lds[buf + 2048 + rb * 32 + ((lg ^ (rb & 3)) << 3)];
        acc[n] = __builtin_amdgcn_mfma_f32_16x16x32_bf16(af, bf, acc[n], 0, 0, 0);
      }
      __builtin_amdgcn_s_setprio(0);
    }
    CFENCE;
    __builtin_amdgcn_s_barrier();
  }
#pragma unroll
  for (int n = 0; n < 7; ++n) {
    int col = 16 * n + lr;
    if (col < NJK) {
#pragma unroll
      for (int i = 0; i < 4; ++i) {
        int b_ = 16 * wv + lg * 4 + i;
        part_rho[((size_t)p * NB + b_) * NJK + col] = acc[n][i];
      }
    }
  }
}

// ---------------------------------------------------------------------------
// K3a: partial p-reduction; K3b: finish + divide by EXACT trace (32 parts).
// ---------------------------------------------------------------------------
__launch_bounds__(128)
__global__ void k3a(const float* __restrict__ part_rho, float* __restrict__ ws2) {
  int blk = blockIdx.x;
  int b = blk >> 1, h = blk & 1;
  int t = threadIdx.x;
  if (t >= NJK) return;
  float s = 0.f;
  for (int pp = 0; pp < 512; ++pp)
    s += part_rho[((size_t)(h * 512 + pp) * NB + b) * NJK + t];
  ws2[(size_t)(h * NB + b) * 128 + t] = s;
}

__launch_bounds__(128)
__global__ void k3b(const float* __restrict__ ws2, const float* __restrict__ part_tr,
                    float* __restrict__ out) {
  int b = blockIdx.x;
  int t = threadIdx.x;
  float tr = 0.f;
#pragma unroll
  for (int i = 0; i < 32; ++i) tr += part_tr[b * 32 + i];
  if (t < NJK) {
    float v = ws2[(size_t)b * 128 + t] + ws2[(size_t)(NB + b) * 128 + t];
    out[b * NJK + t] = v / tr;
  }
}

extern "C" void kernel_launch(void* const* d_in, const int* in_sizes, int n_in,
                              void* d_out, int out_size, void* d_ws, size_t ws_size,
                              hipStream_t stream) {
  const float* X = (const float*)d_in[0];
  const float* rho = (const float*)d_in[1];
  float* out = (float*)d_out;
  char* ws = (char*)d_ws;

  const size_t MB = 1048576ull;
  const size_t need_big = 612 * MB + 65536;
  const size_t need_small = 420 * MB + 65536;

  if (ws_size >= need_big) {
    ushort_t* XHL = (ushort_t*)(ws);              // 128 MiB (i8 pairs)
    ushort_t* XtHL = (ushort_t*)(ws + 128 * MB);  // 128 MiB
    ushort_t* Ahg = (ushort_t*)(ws + 256 * MB);   // 128 MiB
    ushort_t* R2 = (ushort_t*)(ws + 384 * MB);    // 224 MiB
    float* S = (float*)(ws + 608 * MB);           // 4 MiB
    float* part_tr = (float*)(ws + 612 * MB);     // 8 KiB
    float* part_rho = (float*)(ws);               // overlays XHL (dead after k1)
    float* ws2 = (float*)(ws + 32 * MB);

    hipLaunchKernelGGL(p0_rho, dim3(1024), dim3(256), 0, stream, rho, R2, S);
    hipLaunchKernelGGL(p0_split, dim3(16384), dim3(256), 0, stream, X, XHL, XtHL);
    hipLaunchKernelGGL(k1_gemm, dim3(2048), dim3(512), 0, stream, XHL, XtHL, S, Ahg, part_tr, 0);
    hipLaunchKernelGGL(k2_contract, dim3(1024), dim3(256), 0, stream, R2, Ahg, part_rho);
    hipLaunchKernelGGL(k3a, dim3(128), dim3(128), 0, stream, part_rho, ws2);
    hipLaunchKernelGGL(k3b, dim3(64), dim3(128), 0, stream, ws2, part_tr, out);
  } else {
    ushort_t* XHL = (ushort_t*)(ws);              // 32 MiB (per 16-batch group)
    ushort_t* XtHL = (ushort_t*)(ws + 32 * MB);   // 32 MiB
    ushort_t* Ahg = (ushort_t*)(ws + 64 * MB);    // 128 MiB
    ushort_t* R2 = (ushort_t*)(ws + 192 * MB);    // 224 MiB
    float* S = (float*)(ws + 416 * MB);           // 4 MiB
    float* part_tr = (float*)(ws + 420 * MB);     // 8 KiB
    float* part_rho = (float*)(ws);               // overlays XHL+XtHL (dead after k1s)
    float* ws2 = (float*)(ws + 27 * MB);
    if (ws_size < need_small) return;

    hipLaunchKernelGGL(p0_rho, dim3(1024), dim3(256), 0, stream, rho, R2, S);
    for (int g = 0; g < 4; ++g) {
      hipLaunchKernelGGL(p0_split, dim3(4096), dim3(256), 0, stream,
                         X + (size_t)g * 16 * DX * DX, XHL, XtHL);
      hipLaunchKernelGGL(k1_gemm, dim3(512), dim3(512), 0, stream, XHL, XtHL, S, Ahg, part_tr, g * 16);
    }
    hipLaunchKernelGGL(k2_contract, dim3(1024), dim3(256), 0, stream, R2, Ahg, part_rho);
    hipLaunchKernelGGL(k3a, dim3(128), dim3(128), 0, stream, part_rho, ws2);
    hipLaunchKernelGGL(k3b, dim3(64), dim3(128), 0, stream, ws2, part_tr, out);
  }
}